// Round 1
// baseline (714.653 us; speedup 1.0000x reference)
//
#include <hip/hip_runtime.h>

#define B_SZ 16384
#define NLOC 12
#define F_DIM 512
#define H_DIM 256

typedef float f4 __attribute__((ext_vector_type(4)));
typedef _Float16 half4 __attribute__((ext_vector_type(4)));
typedef _Float16 half8 __attribute__((ext_vector_type(8)));

// workspace layout (bytes)
#define OFF_W1   0ul
#define OFF_W2   (OFF_W1 + 512ul*512*2)          // W1: [512][512] f16
#define OFF_C1   (OFF_W2 + 512ul*1024*2)         // W2: [512][1024] f16
#define OFF_CVEC (OFF_C1 + 2048ul)               // c1: [512] f32
#define OFF_T    (OFF_CVEC + 2048ul)             // cvec: [512] f32
#define OFF_ACAT (OFF_T + 16384ul*512*2)         // t: [B][512] f16
#define OFF_LFM  (OFF_ACAT + 16384ul*1024*2)     // Acat: [B][1024] f16 (pooled | g)
// lfm: [B][512] f32

// ---------------------------------------------------------------------------
// Precompute W1[f,f'] = sum_h Wk[f,h] Wq[f',h]   (mode 0)
//            W2[f,j]  = sum_h Wf[h,f] Wv[j,h]            (mode 1, cols 0..511)
//            W2[f,512+j] = S * sum_h Wf[256+h,f] Wv[j,h] (mode 2)
// ---------------------------------------------------------------------------
__global__ void __launch_bounds__(256) precompute_w(
    const float* __restrict__ Wq, const float* __restrict__ Wk,
    const float* __restrict__ Wv, const float* __restrict__ Wf,
    const float* __restrict__ wdr,
    _Float16* __restrict__ W1, _Float16* __restrict__ W2)
{
    __shared__ float X[16][260];
    __shared__ float Y[16][260];
    const int mode = blockIdx.z;
    const int f0 = blockIdx.x * 16;
    const int j0 = blockIdx.y * 16;
    const int t = threadIdx.x;

    {
        const int r = t >> 4, hb = (t & 15) * 16;
        const float* ysrc = ((mode == 0) ? Wq : Wv) + (j0 + r) * H_DIM + hb;
#pragma unroll
        for (int u = 0; u < 16; u += 4)
            *(f4*)&Y[r][hb + u] = *(const f4*)(ysrc + u);
        if (mode == 0) {
            const float* xsrc = Wk + (f0 + r) * H_DIM + hb;
#pragma unroll
            for (int u = 0; u < 16; u += 4)
                *(f4*)&X[r][hb + u] = *(const f4*)(xsrc + u);
        }
    }
    if (mode != 0) {
        const int h = t;                       // 0..255
        const int hoff = (mode == 2) ? H_DIM : 0;
        const float* xsrc = Wf + (long)(h + hoff) * F_DIM + f0;
#pragma unroll
        for (int r = 0; r < 16; ++r) X[r][h] = xsrc[r];
    }
    __syncthreads();

    const int fy = t >> 4, jx = t & 15;
    float acc = 0.f;
#pragma unroll 8
    for (int h = 0; h < H_DIM; ++h) acc += X[fy][h] * Y[jx][h];
    if (mode == 2) {
        float S = 0.f;
#pragma unroll
        for (int k = 0; k < NLOC; ++k) S += wdr[k];
        acc *= S;
    }
    if (mode == 0) W1[(f0 + fy) * F_DIM + (j0 + jx)] = (_Float16)acc;
    else W2[(long)(f0 + fy) * 1024 + ((mode == 2) ? F_DIM : 0) + (j0 + jx)] = (_Float16)acc;
}

// ---------------------------------------------------------------------------
// c1[f]   = sum_h bq[h] Wk[f,h]
// cvec[f] = bv@Wf_top[:,f] + S*(bv@Wf_bot[:,f]) + b_dr*sum(Wf_bot[:,f]) + bf[f]
// ---------------------------------------------------------------------------
__global__ void __launch_bounds__(256) cvec_kernel(
    const float* __restrict__ Wk, const float* __restrict__ Wf,
    const float* __restrict__ bq, const float* __restrict__ bv,
    const float* __restrict__ wdr, const float* __restrict__ bdr,
    const float* __restrict__ bfv,
    float* __restrict__ c1, float* __restrict__ cvec)
{
    const int f = blockIdx.x * 256 + threadIdx.x;   // 0..511
    f4 a = {0.f, 0.f, 0.f, 0.f};
    const f4* wk4 = (const f4*)(Wk + (long)f * H_DIM);
    const f4* bq4 = (const f4*)bq;
#pragma unroll 4
    for (int h4 = 0; h4 < H_DIM / 4; ++h4) a += wk4[h4] * bq4[h4];
    c1[f] = a[0] + a[1] + a[2] + a[3];

    float s1 = 0.f, s2 = 0.f, s3 = 0.f;
#pragma unroll 4
    for (int h = 0; h < H_DIM; ++h) {
        float w1v = Wf[h * F_DIM + f];
        float w2v = Wf[(H_DIM + h) * F_DIM + f];
        float bvh = bv[h];
        s1 += bvh * w1v; s2 += bvh * w2v; s3 += w2v;
    }
    float S = 0.f;
#pragma unroll
    for (int k = 0; k < NLOC; ++k) S += wdr[k];
    cvec[f] = s1 + S * s2 + bdr[0] * s3 + bfv[f];
}

// ---------------------------------------------------------------------------
// Convert global_feature fp32 -> f16 into Acat[:, 512:1024]
// ---------------------------------------------------------------------------
__global__ void __launch_bounds__(256) cvt_g(
    const float* __restrict__ g, _Float16* __restrict__ Acat)
{
    const long i = (long)blockIdx.x * 256 + threadIdx.x;   // 1M threads
    const long row = i >> 6;
    const int c8 = (int)(i & 63) * 8;
    f4 v0 = *(const f4*)(g + row * F_DIM + c8);
    f4 v1 = *(const f4*)(g + row * F_DIM + c8 + 4);
    half8 h;
#pragma unroll
    for (int j = 0; j < 4; ++j) { h[j] = (_Float16)v0[j]; h[4 + j] = (_Float16)v1[j]; }
    *(half8*)(Acat + row * 1024 + F_DIM + c8) = h;
}

// ---------------------------------------------------------------------------
// Generic MFMA GEMM: C[m,n] = sum_k A[m,k] * Bt[n,k], M=16384, N=512.
// Block tile 64x64, 4 waves in 2x2, each wave 32x32 via 2x2 mfma_f32_16x16x32_f16.
// EPI 0: outh = (f16)(acc + addvec[n])                     (K_t)
// EPI 1: outf = relu(acc + addvec[n]) + lfm[m,n] + gf[m,n] (K_final)
// ---------------------------------------------------------------------------
template<int EPI>
__global__ void __launch_bounds__(256) gemm_bt(
    const _Float16* __restrict__ A, long lda,
    const _Float16* __restrict__ Bt, int K,
    _Float16* __restrict__ outh, float* __restrict__ outf,
    const float* __restrict__ addvec,
    const float* __restrict__ lfm, const float* __restrict__ gfeat)
{
    __shared__ _Float16 As[64][40];   // +8 pad: 2-way-max LDS banking
    __shared__ _Float16 Bs[64][40];
    const int tid = threadIdx.x;
    const int lane = tid & 63;
    const int wave = tid >> 6;
    const int wm = (wave & 1) * 32;
    const int wn = (wave >> 1) * 32;
    const long m0 = (long)blockIdx.x * 64;
    const int n0 = blockIdx.y * 64;
    const int quad = lane >> 4;
    const int l16 = lane & 15;
    const int sr = tid >> 2;          // stage row 0..63
    const int sc = (tid & 3) * 8;     // stage col 0/8/16/24

    f4 acc[2][2] = {{{0.f,0.f,0.f,0.f},{0.f,0.f,0.f,0.f}},
                    {{0.f,0.f,0.f,0.f},{0.f,0.f,0.f,0.f}}};

    const _Float16* Aptr = A + (m0 + sr) * lda + sc;
    const _Float16* Bptr = Bt + (long)(n0 + sr) * K + sc;

    for (int k0 = 0; k0 < K; k0 += 32) {
        uint4 av = *(const uint4*)(Aptr + k0);
        uint4 bv = *(const uint4*)(Bptr + k0);
        *(uint4*)(&As[sr][sc]) = av;
        *(uint4*)(&Bs[sr][sc]) = bv;
        __syncthreads();
        half8 a0 = *(const half8*)(&As[wm + l16][quad * 8]);
        half8 a1 = *(const half8*)(&As[wm + 16 + l16][quad * 8]);
        half8 b0 = *(const half8*)(&Bs[wn + l16][quad * 8]);
        half8 b1 = *(const half8*)(&Bs[wn + 16 + l16][quad * 8]);
        acc[0][0] = __builtin_amdgcn_mfma_f32_16x16x32_f16(a0, b0, acc[0][0], 0, 0, 0);
        acc[0][1] = __builtin_amdgcn_mfma_f32_16x16x32_f16(a0, b1, acc[0][1], 0, 0, 0);
        acc[1][0] = __builtin_amdgcn_mfma_f32_16x16x32_f16(a1, b0, acc[1][0], 0, 0, 0);
        acc[1][1] = __builtin_amdgcn_mfma_f32_16x16x32_f16(a1, b1, acc[1][1], 0, 0, 0);
        __syncthreads();
    }

#pragma unroll
    for (int mi = 0; mi < 2; ++mi)
#pragma unroll
        for (int ni = 0; ni < 2; ++ni) {
            const int col = n0 + wn + ni * 16 + l16;       // C/D: col = lane&15
            const float av = addvec[col];
#pragma unroll
            for (int i = 0; i < 4; ++i) {
                const long row = m0 + wm + mi * 16 + quad * 4 + i;  // row = quad*4+reg
                float v = acc[mi][ni][i] + av;
                if constexpr (EPI == 0) {
                    outh[row * F_DIM + col] = (_Float16)v;
                } else {
                    v = fmaxf(v, 0.f) + lfm[row * F_DIM + col] + gfeat[row * F_DIM + col];
                    outf[row * F_DIM + col] = v;
                }
            }
        }
}

// ---------------------------------------------------------------------------
// Per-row local pass: one wave per batch row b.
// s2[k] = (loc[b,k,:] . t[b,:]) / 16 ; a2 = softmax ; pooled = sum a2*loc ;
// lfm = sum wdr*loc + b_dr. Locals stay register-resident (12 x 8 floats/lane).
// ---------------------------------------------------------------------------
__global__ void __launch_bounds__(256) local_pass(
    const float* __restrict__ loc, const _Float16* __restrict__ tbuf,
    const float* __restrict__ wdr, const float* __restrict__ bdr,
    _Float16* __restrict__ Acat, float* __restrict__ lfm)
{
    const int wave = threadIdx.x >> 6;
    const int lane = threadIdx.x & 63;
    const long b = (long)blockIdx.x * 4 + wave;
    const int c0 = lane * 4;
    const int c1 = 256 + lane * 4;
    const float* lb = loc + b * (NLOC * F_DIM);

    f4 la[NLOC], lbv[NLOC];
#pragma unroll
    for (int k = 0; k < NLOC; ++k) {
        la[k]  = *(const f4*)(lb + k * F_DIM + c0);
        lbv[k] = *(const f4*)(lb + k * F_DIM + c1);
    }
    half4 ta = *(const half4*)(tbuf + b * F_DIM + c0);
    half4 tb = *(const half4*)(tbuf + b * F_DIM + c1);
    f4 taf = __builtin_convertvector(ta, f4);
    f4 tbf = __builtin_convertvector(tb, f4);

    float p[NLOC];
#pragma unroll
    for (int k = 0; k < NLOC; ++k) {
        f4 prod = la[k] * taf + lbv[k] * tbf;
        p[k] = prod[0] + prod[1] + prod[2] + prod[3];
    }
#pragma unroll
    for (int k = 0; k < NLOC; ++k) {
        float v = p[k];
        v += __shfl_xor(v, 1);
        v += __shfl_xor(v, 2);
        v += __shfl_xor(v, 4);
        v += __shfl_xor(v, 8);
        v += __shfl_xor(v, 16);
        v += __shfl_xor(v, 32);
        p[k] = v * 0.0625f;   // scale = 1/sqrt(256)
    }
    float mx = p[0];
#pragma unroll
    for (int k = 1; k < NLOC; ++k) mx = fmaxf(mx, p[k]);
    float e[NLOC], s = 0.f;
#pragma unroll
    for (int k = 0; k < NLOC; ++k) { e[k] = expf(p[k] - mx); s += e[k]; }
    const float inv = 1.f / s;

    f4 pA = {0.f,0.f,0.f,0.f}, pB = {0.f,0.f,0.f,0.f};
    f4 fA = {0.f,0.f,0.f,0.f}, fB = {0.f,0.f,0.f,0.f};
#pragma unroll
    for (int k = 0; k < NLOC; ++k) {
        const float ak = e[k] * inv;
        const float wk = wdr[k];
        pA += ak * la[k]; pB += ak * lbv[k];
        fA += wk * la[k]; fB += wk * lbv[k];
    }
    const float bd = bdr[0];
    fA += bd; fB += bd;
    *(half4*)(Acat + b * 1024 + c0) = __builtin_convertvector(pA, half4);
    *(half4*)(Acat + b * 1024 + c1) = __builtin_convertvector(pB, half4);
    *(f4*)(lfm + b * F_DIM + c0) = fA;
    *(f4*)(lfm + b * F_DIM + c1) = fB;
}

// ---------------------------------------------------------------------------
extern "C" void kernel_launch(void* const* d_in, const int* in_sizes, int n_in,
                              void* d_out, int out_size, void* d_ws, size_t ws_size,
                              hipStream_t stream)
{
    (void)in_sizes; (void)n_in; (void)out_size; (void)ws_size;
    const float* gf  = (const float*)d_in[0];
    const float* loc = (const float*)d_in[1];
    const float* Wq  = (const float*)d_in[2];
    const float* bq  = (const float*)d_in[3];
    const float* Wk  = (const float*)d_in[4];
    // d_in[5] = bk: dropped — contributes only a k-constant to s2 (softmax-invariant)
    const float* Wv  = (const float*)d_in[6];
    const float* bv  = (const float*)d_in[7];
    const float* wdr = (const float*)d_in[8];
    const float* bdr = (const float*)d_in[9];
    const float* Wf  = (const float*)d_in[10];
    const float* bfv = (const float*)d_in[11];
    float* out = (float*)d_out;

    char* ws = (char*)d_ws;
    _Float16* W1   = (_Float16*)(ws + OFF_W1);
    _Float16* W2   = (_Float16*)(ws + OFF_W2);
    float*    c1   = (float*)(ws + OFF_C1);
    float*    cvec = (float*)(ws + OFF_CVEC);
    _Float16* tbuf = (_Float16*)(ws + OFF_T);
    _Float16* Acat = (_Float16*)(ws + OFF_ACAT);
    float*    lfm  = (float*)(ws + OFF_LFM);

    precompute_w<<<dim3(32, 32, 3), 256, 0, stream>>>(Wq, Wk, Wv, Wf, wdr, W1, W2);
    cvec_kernel<<<2, 256, 0, stream>>>(Wk, Wf, bq, bv, wdr, bdr, bfv, c1, cvec);
    cvt_g<<<4096, 256, 0, stream>>>(gf, Acat);
    // t = g @ W1^T + c1   (A = Acat[:,512:], lda=1024)
    gemm_bt<0><<<dim3(256, 8), 256, 0, stream>>>(Acat + F_DIM, 1024, W1, 512,
                                                 tbuf, nullptr, c1, nullptr, nullptr);
    local_pass<<<4096, 256, 0, stream>>>(loc, tbuf, wdr, bdr, Acat, lfm);
    // out = relu([pooled,g] @ W2^T + cvec) + lfm + g   (K=1024)
    gemm_bt<1><<<dim3(256, 8), 256, 0, stream>>>(Acat, 1024, W2, 1024,
                                                 nullptr, out, cvec, lfm, gf);
}

// Round 2
// 710.413 us; speedup vs baseline: 1.0060x; 1.0060x over previous
//
#include <hip/hip_runtime.h>

#define NLOC 12
#define F_DIM 512
#define H_DIM 256

typedef float f4 __attribute__((ext_vector_type(4)));
typedef _Float16 half4 __attribute__((ext_vector_type(4)));
typedef _Float16 half8 __attribute__((ext_vector_type(8)));

// workspace layout (bytes)
#define OFF_W1   0ul
#define OFF_W2   (OFF_W1 + 512ul*512*2)          // W1: [512][512] f16
#define OFF_C1   (OFF_W2 + 512ul*1024*2)         // W2: [512][1024] f16
#define OFF_CVEC (OFF_C1 + 2048ul)               // c1: [512] f32
#define OFF_ACAT (OFF_CVEC + 2048ul)             // cvec: [512] f32
#define OFF_BASE (OFF_ACAT + 16384ul*1024*2)     // Acat: [B][1024] f16 (pooled | g)
// base: [B][512] f16  (lfm + g)

// ---------------------------------------------------------------------------
// Precompute W1[f,f'] = sum_h Wk[f,h] Wq[f',h]   (mode 0)
//            W2[f,j]  = sum_h Wf[h,f] Wv[j,h]            (mode 1, cols 0..511)
//            W2[f,512+j] = S * sum_h Wf[256+h,f] Wv[j,h] (mode 2)
// 32x32 tile, 2x2 outputs/thread (halves LDS traffic vs 16x16/1x1).
// ---------------------------------------------------------------------------
__global__ void __launch_bounds__(256) precompute_w(
    const float* __restrict__ Wq, const float* __restrict__ Wk,
    const float* __restrict__ Wv, const float* __restrict__ Wf,
    const float* __restrict__ wdr,
    _Float16* __restrict__ W1, _Float16* __restrict__ W2)
{
    __shared__ float X[32][264];
    __shared__ float Y[32][264];
    const int mode = blockIdx.z;
    const int f0 = blockIdx.x * 32;
    const int j0 = blockIdx.y * 32;
    const int t = threadIdx.x;

    {
        const int r = t >> 3, cb = (t & 7) * 32;
        const float* ysrc = ((mode == 0) ? Wq : Wv) + (j0 + r) * H_DIM + cb;
#pragma unroll
        for (int u = 0; u < 32; u += 4)
            *(f4*)&Y[r][cb + u] = *(const f4*)(ysrc + u);
        if (mode == 0) {
            const float* xsrc = Wk + (f0 + r) * H_DIM + cb;
#pragma unroll
            for (int u = 0; u < 32; u += 4)
                *(f4*)&X[r][cb + u] = *(const f4*)(xsrc + u);
        }
    }
    if (mode != 0) {
        const int h = t;                       // 0..255
        const int hoff = (mode == 2) ? H_DIM : 0;
        const float* xsrc = Wf + (long)(h + hoff) * F_DIM + f0;
        f4 v[8];
#pragma unroll
        for (int u = 0; u < 8; ++u) v[u] = *(const f4*)(xsrc + u * 4);
#pragma unroll
        for (int r = 0; r < 32; ++r) X[r][h] = v[r >> 2][r & 3];
    }
    __syncthreads();

    const int fy = t >> 4, jx = t & 15;
    float a00 = 0.f, a01 = 0.f, a10 = 0.f, a11 = 0.f;
#pragma unroll 8
    for (int h = 0; h < H_DIM; ++h) {
        float x0 = X[fy][h], x1 = X[fy + 16][h];
        float y0 = Y[jx][h], y1 = Y[jx + 16][h];
        a00 += x0 * y0; a01 += x0 * y1; a10 += x1 * y0; a11 += x1 * y1;
    }
    if (mode == 2) {
        float S = 0.f;
#pragma unroll
        for (int k = 0; k < NLOC; ++k) S += wdr[k];
        a00 *= S; a01 *= S; a10 *= S; a11 *= S;
    }
    if (mode == 0) {
        W1[(f0 + fy) * F_DIM + (j0 + jx)]             = (_Float16)a00;
        W1[(f0 + fy) * F_DIM + (j0 + jx + 16)]        = (_Float16)a01;
        W1[(f0 + fy + 16) * F_DIM + (j0 + jx)]        = (_Float16)a10;
        W1[(f0 + fy + 16) * F_DIM + (j0 + jx + 16)]   = (_Float16)a11;
    } else {
        const long co = (mode == 2) ? F_DIM : 0;
        W2[(long)(f0 + fy) * 1024 + co + (j0 + jx)]           = (_Float16)a00;
        W2[(long)(f0 + fy) * 1024 + co + (j0 + jx + 16)]      = (_Float16)a01;
        W2[(long)(f0 + fy + 16) * 1024 + co + (j0 + jx)]      = (_Float16)a10;
        W2[(long)(f0 + fy + 16) * 1024 + co + (j0 + jx + 16)] = (_Float16)a11;
    }
}

// ---------------------------------------------------------------------------
// c1[f]   = sum_h bq[h] Wk[f,h]
// cvec[f] = bv@Wf_top[:,f] + S*(bv@Wf_bot[:,f]) + b_dr*sum(Wf_bot[:,f]) + bf[f]
// ---------------------------------------------------------------------------
__global__ void __launch_bounds__(256) cvec_kernel(
    const float* __restrict__ Wk, const float* __restrict__ Wf,
    const float* __restrict__ bq, const float* __restrict__ bv,
    const float* __restrict__ wdr, const float* __restrict__ bdr,
    const float* __restrict__ bfv,
    float* __restrict__ c1, float* __restrict__ cvec)
{
    const int f = blockIdx.x * 256 + threadIdx.x;   // 0..511
    f4 a = {0.f, 0.f, 0.f, 0.f};
    const f4* wk4 = (const f4*)(Wk + (long)f * H_DIM);
    const f4* bq4 = (const f4*)bq;
#pragma unroll 4
    for (int h4 = 0; h4 < H_DIM / 4; ++h4) a += wk4[h4] * bq4[h4];
    c1[f] = a[0] + a[1] + a[2] + a[3];

    float s1 = 0.f, s2 = 0.f, s3 = 0.f;
#pragma unroll 4
    for (int h = 0; h < H_DIM; ++h) {
        float w1v = Wf[h * F_DIM + f];
        float w2v = Wf[(H_DIM + h) * F_DIM + f];
        float bvh = bv[h];
        s1 += bvh * w1v; s2 += bvh * w2v; s3 += w2v;
    }
    float S = 0.f;
#pragma unroll
    for (int k = 0; k < NLOC; ++k) S += wdr[k];
    cvec[f] = s1 + S * s2 + bdr[0] * s3 + bfv[f];
}

// ---------------------------------------------------------------------------
// K1: fused  (g->f16) + (t = g@W1^T + c1, MFMA, T kept in LDS) + local pass.
// Block = 32 rows. LDS: G[32][520] + T[32][520] + Bs[128][40] = 76.8 KB
// -> 2 blocks/CU. Grid 512 blocks.
// Outputs: Acat[b][0:512]=pooled f16, Acat[b][512:1024]=g f16,
//          base[b][0:512] = (lfm + g) f16.
// ---------------------------------------------------------------------------
__global__ void __launch_bounds__(256) fused_local(
    const float* __restrict__ g, const float* __restrict__ loc,
    const _Float16* __restrict__ W1, const float* __restrict__ c1,
    const float* __restrict__ wdr, const float* __restrict__ bdr,
    _Float16* __restrict__ Acat, _Float16* __restrict__ base)
{
    __shared__ _Float16 G[32][520];
    __shared__ _Float16 T[32][520];
    __shared__ _Float16 Bs[128][40];
    const int tid = threadIdx.x;
    const int lane = tid & 63;
    const int wave = tid >> 6;
    const int quad = lane >> 4;
    const int l16 = lane & 15;
    const long m0 = (long)blockIdx.x * 32;

    // ---- stage G (f32 -> f16), coalesced: 8 lanes cover 64 consecutive floats
    {
        const int r = tid >> 3;          // 0..31
        const int cb = (tid & 7) * 8;
#pragma unroll
        for (int u = 0; u < 512; u += 64) {
            const float* src = g + (m0 + r) * F_DIM + cb + u;
            f4 v0 = *(const f4*)(src);
            f4 v1 = *(const f4*)(src + 4);
            half8 hv;
#pragma unroll
            for (int j = 0; j < 4; ++j) { hv[j] = (_Float16)v0[j]; hv[4 + j] = (_Float16)v1[j]; }
            *(half8*)&G[r][cb + u] = hv;
        }
    }
    __syncthreads();

    // ---- phase 1: T = G @ W1^T + c1 (4 n-tiles of 128, wave owns 32 cols)
    const int srB = tid >> 1, scB = (tid & 1) * 16;
    const int wn1 = wave * 32;
    for (int nt = 0; nt < 4; ++nt) {
        const int n0 = nt * 128;
        f4 acc[2][2] = {{{0.f,0.f,0.f,0.f},{0.f,0.f,0.f,0.f}},
                        {{0.f,0.f,0.f,0.f},{0.f,0.f,0.f,0.f}}};
        for (int k0 = 0; k0 < 512; k0 += 32) {
            const _Float16* wsrc = W1 + (n0 + srB) * F_DIM + k0 + scB;
            uint4 w0 = *(const uint4*)(wsrc);
            uint4 w1 = *(const uint4*)(wsrc + 8);
            *(uint4*)&Bs[srB][scB] = w0;
            *(uint4*)&Bs[srB][scB + 8] = w1;
            __syncthreads();
            half8 a0 = *(const half8*)&G[l16][k0 + quad * 8];
            half8 a1 = *(const half8*)&G[16 + l16][k0 + quad * 8];
            half8 b0 = *(const half8*)&Bs[wn1 + l16][quad * 8];
            half8 b1 = *(const half8*)&Bs[wn1 + 16 + l16][quad * 8];
            acc[0][0] = __builtin_amdgcn_mfma_f32_16x16x32_f16(a0, b0, acc[0][0], 0, 0, 0);
            acc[0][1] = __builtin_amdgcn_mfma_f32_16x16x32_f16(a0, b1, acc[0][1], 0, 0, 0);
            acc[1][0] = __builtin_amdgcn_mfma_f32_16x16x32_f16(a1, b0, acc[1][0], 0, 0, 0);
            acc[1][1] = __builtin_amdgcn_mfma_f32_16x16x32_f16(a1, b1, acc[1][1], 0, 0, 0);
            __syncthreads();
        }
#pragma unroll
        for (int ni = 0; ni < 2; ++ni) {
            const int col = n0 + wn1 + ni * 16 + l16;
            const float cv = c1[col];
#pragma unroll
            for (int mi = 0; mi < 2; ++mi)
#pragma unroll
                for (int i = 0; i < 4; ++i)
                    T[mi * 16 + quad * 4 + i][col] = (_Float16)(acc[mi][ni][i] + cv);
        }
    }
    __syncthreads();

    // ---- phase 2: local pass, 8 rows per wave, t & g served from LDS
    const int c0 = lane * 4;
    const int c1i = 256 + lane * 4;
    const float bd = bdr[0];
    float wv[NLOC];
#pragma unroll
    for (int k = 0; k < NLOC; ++k) wv[k] = wdr[k];

    for (int rr = 0; rr < 8; ++rr) {
        const int bl = wave * 8 + rr;
        const long b = m0 + bl;
        const float* lb = loc + b * (NLOC * F_DIM);

        f4 la[NLOC], lbv[NLOC];
#pragma unroll
        for (int k = 0; k < NLOC; ++k) {
            la[k]  = *(const f4*)(lb + k * F_DIM + c0);
            lbv[k] = *(const f4*)(lb + k * F_DIM + c1i);
        }
        f4 taf = __builtin_convertvector(*(const half4*)&T[bl][c0], f4);
        f4 tbf = __builtin_convertvector(*(const half4*)&T[bl][c1i], f4);

        float p[NLOC];
#pragma unroll
        for (int k = 0; k < NLOC; ++k) {
            f4 prod = la[k] * taf + lbv[k] * tbf;
            p[k] = prod[0] + prod[1] + prod[2] + prod[3];
        }
#pragma unroll
        for (int k = 0; k < NLOC; ++k) {
            float v = p[k];
            v += __shfl_xor(v, 1);
            v += __shfl_xor(v, 2);
            v += __shfl_xor(v, 4);
            v += __shfl_xor(v, 8);
            v += __shfl_xor(v, 16);
            v += __shfl_xor(v, 32);
            p[k] = v * 0.0625f;   // scale = 1/sqrt(256)
        }
        float mx = p[0];
#pragma unroll
        for (int k = 1; k < NLOC; ++k) mx = fmaxf(mx, p[k]);
        float e[NLOC], s = 0.f;
#pragma unroll
        for (int k = 0; k < NLOC; ++k) { e[k] = expf(p[k] - mx); s += e[k]; }
        const float inv = 1.f / s;

        f4 pA = {0.f,0.f,0.f,0.f}, pB = {0.f,0.f,0.f,0.f};
        f4 fA = {0.f,0.f,0.f,0.f}, fB = {0.f,0.f,0.f,0.f};
#pragma unroll
        for (int k = 0; k < NLOC; ++k) {
            const float ak = e[k] * inv;
            const float wk = wv[k];
            pA += ak * la[k]; pB += ak * lbv[k];
            fA += wk * la[k]; fB += wk * lbv[k];
        }
        half4 gA = *(const half4*)&G[bl][c0];
        half4 gB = *(const half4*)&G[bl][c1i];
        fA += bd + __builtin_convertvector(gA, f4);
        fB += bd + __builtin_convertvector(gB, f4);

        *(half4*)(Acat + b * 1024 + c0)          = __builtin_convertvector(pA, half4);
        *(half4*)(Acat + b * 1024 + c1i)         = __builtin_convertvector(pB, half4);
        *(half4*)(Acat + b * 1024 + 512 + c0)    = gA;
        *(half4*)(Acat + b * 1024 + 512 + c1i)   = gB;
        *(half4*)(base + b * F_DIM + c0)         = __builtin_convertvector(fA, half4);
        *(half4*)(base + b * F_DIM + c1i)        = __builtin_convertvector(fB, half4);
    }
}

// ---------------------------------------------------------------------------
// K2: out = relu(Acat @ W2^T + cvec) + base.  M=16384, N=512, K=1024.
// Block tile 64x128, 4 waves 2x2, each wave 32x64 (2x4 mfma 16x16x32).
// ---------------------------------------------------------------------------
__global__ void __launch_bounds__(256) gemm_final(
    const _Float16* __restrict__ A, const _Float16* __restrict__ Bt,
    const float* __restrict__ cvec, const _Float16* __restrict__ base,
    float* __restrict__ out)
{
    __shared__ _Float16 As[64][40];
    __shared__ _Float16 Bs[128][40];
    const int tid = threadIdx.x;
    const int lane = tid & 63;
    const int wave = tid >> 6;
    const int quad = lane >> 4;
    const int l16 = lane & 15;
    const int wm = (wave & 1) * 32;
    const int wn = (wave >> 1) * 64;
    const long m0 = (long)blockIdx.x * 64;
    const int n0 = blockIdx.y * 128;
    const int srA = tid >> 2, scA = (tid & 3) * 8;
    const int srB = tid >> 1, scB = (tid & 1) * 16;

    f4 acc[2][4];
#pragma unroll
    for (int mi = 0; mi < 2; ++mi)
#pragma unroll
        for (int nj = 0; nj < 4; ++nj) acc[mi][nj] = (f4){0.f,0.f,0.f,0.f};

    for (int k0 = 0; k0 < 1024; k0 += 32) {
        uint4 av = *(const uint4*)(A + (m0 + srA) * 1024 + k0 + scA);
        const _Float16* bsrc = Bt + (long)(n0 + srB) * 1024 + k0 + scB;
        uint4 b0v = *(const uint4*)(bsrc);
        uint4 b1v = *(const uint4*)(bsrc + 8);
        *(uint4*)&As[srA][scA] = av;
        *(uint4*)&Bs[srB][scB] = b0v;
        *(uint4*)&Bs[srB][scB + 8] = b1v;
        __syncthreads();
        half8 a0 = *(const half8*)&As[wm + l16][quad * 8];
        half8 a1 = *(const half8*)&As[wm + 16 + l16][quad * 8];
        half8 bf[4];
#pragma unroll
        for (int nj = 0; nj < 4; ++nj)
            bf[nj] = *(const half8*)&Bs[wn + nj * 16 + l16][quad * 8];
#pragma unroll
        for (int nj = 0; nj < 4; ++nj) {
            acc[0][nj] = __builtin_amdgcn_mfma_f32_16x16x32_f16(a0, bf[nj], acc[0][nj], 0, 0, 0);
            acc[1][nj] = __builtin_amdgcn_mfma_f32_16x16x32_f16(a1, bf[nj], acc[1][nj], 0, 0, 0);
        }
        __syncthreads();
    }

#pragma unroll
    for (int mi = 0; mi < 2; ++mi)
#pragma unroll
        for (int nj = 0; nj < 4; ++nj) {
            const int col = n0 + wn + nj * 16 + l16;
            const float cv = cvec[col];
#pragma unroll
            for (int i = 0; i < 4; ++i) {
                const long row = m0 + wm + mi * 16 + quad * 4 + i;
                float v = acc[mi][nj][i] + cv;
                v = fmaxf(v, 0.f) + (float)base[row * F_DIM + col];
                out[row * F_DIM + col] = v;
            }
        }
}

// ---------------------------------------------------------------------------
extern "C" void kernel_launch(void* const* d_in, const int* in_sizes, int n_in,
                              void* d_out, int out_size, void* d_ws, size_t ws_size,
                              hipStream_t stream)
{
    (void)in_sizes; (void)n_in; (void)out_size; (void)ws_size;
    const float* gf  = (const float*)d_in[0];
    const float* loc = (const float*)d_in[1];
    const float* Wq  = (const float*)d_in[2];
    const float* bq  = (const float*)d_in[3];
    const float* Wk  = (const float*)d_in[4];
    // d_in[5] = bk: dropped — contributes only a k-constant to s2 (softmax-invariant)
    const float* Wv  = (const float*)d_in[6];
    const float* bv  = (const float*)d_in[7];
    const float* wdr = (const float*)d_in[8];
    const float* bdr = (const float*)d_in[9];
    const float* Wf  = (const float*)d_in[10];
    const float* bfv = (const float*)d_in[11];
    float* out = (float*)d_out;

    char* ws = (char*)d_ws;
    _Float16* W1   = (_Float16*)(ws + OFF_W1);
    _Float16* W2   = (_Float16*)(ws + OFF_W2);
    float*    c1   = (float*)(ws + OFF_C1);
    float*    cvec = (float*)(ws + OFF_CVEC);
    _Float16* Acat = (_Float16*)(ws + OFF_ACAT);
    _Float16* base = (_Float16*)(ws + OFF_BASE);

    precompute_w<<<dim3(16, 16, 3), 256, 0, stream>>>(Wq, Wk, Wv, Wf, wdr, W1, W2);
    cvec_kernel<<<2, 256, 0, stream>>>(Wk, Wf, bq, bv, wdr, bdr, bfv, c1, cvec);
    fused_local<<<512, 256, 0, stream>>>(gf, loc, W1, c1, wdr, bdr, Acat, base);
    gemm_final<<<dim3(256, 4), 256, 0, stream>>>(Acat, W2, cvec, base, out);
}